// Round 1
// baseline (13972.276 us; speedup 1.0000x reference)
//
#include <hip/hip_runtime.h>
#include <math.h>

// GCN on MI355X. N=200000 nodes, E=6400000 edges.
// Decomposition per layer:  g[i] = dinv[i] * (act[i] @ W)
//   agg[d] = g[d] + sum_{e: dst=d} g[src_e]          (self-loop + scatter)
//   act'[d] = activation(dinv[d]*agg[d] + b)
// deg/dinv depends only on edges -> computed once, reused by all 3 layers.

static constexpr int NN = 200000;
static constexpr int NE = 6400000;

// ---------- degree / dinv ----------
__global__ void k_deg_init(float* __restrict__ deg, int n) {
  int i = blockIdx.x * blockDim.x + threadIdx.x;
  if (i < n) deg[i] = 1.0f;  // self-loop
}

__global__ void k_deg_count(const int* __restrict__ dst, float* __restrict__ deg, int e) {
  int i = blockIdx.x * blockDim.x + threadIdx.x;
  if (i < e) atomicAdd(deg + dst[i], 1.0f);
}

__global__ void k_dinv(float* __restrict__ deg, int n) {
  int i = blockIdx.x * blockDim.x + threadIdx.x;
  if (i < n) deg[i] = 1.0f / sqrtf(deg[i]);
}

// ---------- node transform: g[i] = dinv[i] * (act[i] @ W) ----------
template <int FIN, int FOUT>
__global__ void k_transform(const float* __restrict__ act, const float* __restrict__ W,
                            const float* __restrict__ dinv, float* __restrict__ g, int n) {
  __shared__ float sW[FIN * FOUT];
  for (int t = threadIdx.x; t < FIN * FOUT; t += blockDim.x) sW[t] = W[t];
  __syncthreads();
  int i = blockIdx.x * blockDim.x + threadIdx.x;
  if (i >= n) return;
  float a[FIN];
#pragma unroll
  for (int k = 0; k < FIN; ++k) a[k] = act[(size_t)i * FIN + k];
  float di = dinv[i];
#pragma unroll
  for (int j = 0; j < FOUT; ++j) {
    float s = 0.f;
#pragma unroll
    for (int k = 0; k < FIN; ++k) s = fmaf(a[k], sW[k * FOUT + j], s);
    g[(size_t)i * FOUT + j] = di * s;
  }
}

// ---------- vector copy (self-loop init: agg := g) ----------
__global__ void k_copy4(const float4* __restrict__ src, float4* __restrict__ dst, int nw) {
  int i = blockIdx.x * blockDim.x + threadIdx.x;
  if (i < nw) dst[i] = src[i];
}

// ---------- edge scatter: agg[dst] += g[src] ----------
template <int FOUT>
__global__ void k_scatter(const int* __restrict__ srcI, const int* __restrict__ dstI,
                          const float* __restrict__ g, float* __restrict__ agg, int e) {
  int i = blockIdx.x * blockDim.x + threadIdx.x;
  if (i >= e) return;
  int s = srcI[i];
  int d = dstI[i];
  const float* gs = g + (size_t)s * FOUT;
  float* ad = agg + (size_t)d * FOUT;
  if constexpr (FOUT % 4 == 0) {
#pragma unroll
    for (int j = 0; j < FOUT; j += 4) {
      float4 v = *(const float4*)(gs + j);  // row base is 16B-aligned for FOUT=12,24
      atomicAdd(ad + j + 0, v.x);
      atomicAdd(ad + j + 1, v.y);
      atomicAdd(ad + j + 2, v.z);
      atomicAdd(ad + j + 3, v.w);
    }
  } else {
#pragma unroll
    for (int j = 0; j < FOUT; j += 2) {
      float2 v = *(const float2*)(gs + j);  // FOUT=6: rows 24B -> 8B-aligned
      atomicAdd(ad + j + 0, v.x);
      atomicAdd(ad + j + 1, v.y);
    }
  }
}

// ---------- finalize: act' = activation(dinv*agg + b) ----------
// MODE 0: tanh   MODE 1: l2norm then tanh   MODE 2: l2norm
template <int FOUT, int MODE>
__global__ void k_finalize(const float* __restrict__ agg, const float* __restrict__ b,
                           const float* __restrict__ dinv, float* __restrict__ out, int n) {
  int i = blockIdx.x * blockDim.x + threadIdx.x;
  if (i >= n) return;
  float di = dinv[i];
  float v[FOUT];
  float ss = 0.f;
#pragma unroll
  for (int j = 0; j < FOUT; ++j) {
    float t = fmaf(di, agg[(size_t)i * FOUT + j], b[j]);
    v[j] = t;
    ss += t * t;
  }
  if (MODE == 0) {
#pragma unroll
    for (int j = 0; j < FOUT; ++j) v[j] = tanhf(v[j]);
  } else {
    float inv = 1.f / fmaxf(sqrtf(ss), 1e-12f);
#pragma unroll
    for (int j = 0; j < FOUT; ++j) {
      float t = v[j] * inv;
      v[j] = (MODE == 1) ? tanhf(t) : t;
    }
  }
#pragma unroll
  for (int j = 0; j < FOUT; ++j) out[(size_t)i * FOUT + j] = v[j];
}

// ---------- classifier: out = l2norm(act @ Wc + bc) ----------
__global__ void k_classifier(const float* __restrict__ act, const float* __restrict__ Wc,
                             const float* __restrict__ bc, float* __restrict__ out, int n) {
  __shared__ float sW[24 * 13];
  __shared__ float sb[13];
  for (int t = threadIdx.x; t < 24 * 13; t += blockDim.x) sW[t] = Wc[t];
  if (threadIdx.x < 13) sb[threadIdx.x] = bc[threadIdx.x];
  __syncthreads();
  int i = blockIdx.x * blockDim.x + threadIdx.x;
  if (i >= n) return;
  float a[24];
#pragma unroll
  for (int k = 0; k < 24; ++k) a[k] = act[(size_t)i * 24 + k];
  float v[13];
  float ss = 0.f;
#pragma unroll
  for (int j = 0; j < 13; ++j) {
    float s = sb[j];
#pragma unroll
    for (int k = 0; k < 24; ++k) s = fmaf(a[k], sW[k * 13 + j], s);
    v[j] = s;
    ss += s * s;
  }
  float inv = 1.f / fmaxf(sqrtf(ss), 1e-12f);
#pragma unroll
  for (int j = 0; j < 13; ++j) out[(size_t)i * 13 + j] = v[j] * inv;
}

extern "C" void kernel_launch(void* const* d_in, const int* in_sizes, int n_in,
                              void* d_out, int out_size, void* d_ws, size_t ws_size,
                              hipStream_t stream) {
  const float* x  = (const float*)d_in[0];
  const int*   ei = (const int*)d_in[1];   // edge_index [2,E] as int32
  const float* W1 = (const float*)d_in[2];
  const float* b1 = (const float*)d_in[3];
  const float* W2 = (const float*)d_in[4];
  const float* b2 = (const float*)d_in[5];
  const float* W3 = (const float*)d_in[6];
  const float* b3 = (const float*)d_in[7];
  const float* Wc = (const float*)d_in[8];
  const float* bc = (const float*)d_in[9];
  float* out = (float*)d_out;

  const int n = NN;
  const int e = NE;
  const int* srcI = ei;       // row 0
  const int* dstI = ei + e;   // row 1

  // Workspace layout (floats): dinv[N] | A[N*24] | B[N*24]  = 39.2 MB
  float* ws = (float*)d_ws;
  float* dinv = ws;
  float* A = ws + n;
  float* B = A + (size_t)n * 24;

  const int BK = 256;
  const int gn = (n + BK - 1) / BK;
  const int ge = (e + BK - 1) / BK;

  // --- degree / dinv (shared by all layers) ---
  k_deg_init<<<gn, BK, 0, stream>>>(dinv, n);
  k_deg_count<<<ge, BK, 0, stream>>>(dstI, dinv, e);
  k_dinv<<<gn, BK, 0, stream>>>(dinv, n);

  // --- Layer 1: x[N,3] -> act1 in A[N,6], tanh ---
  k_transform<3, 6><<<gn, BK, 0, stream>>>(x, W1, dinv, A, n);                 // g in A
  k_copy4<<<(n * 6 / 4 + BK - 1) / BK, BK, 0, stream>>>((const float4*)A, (float4*)B, n * 6 / 4);
  k_scatter<6><<<ge, BK, 0, stream>>>(srcI, dstI, A, B, e);                    // agg in B
  k_finalize<6, 0><<<gn, BK, 0, stream>>>(B, b1, dinv, A, n);                  // act1 in A

  // --- Layer 2: A[N,6] -> act2 in B[N,12], l2norm+tanh ---
  k_transform<6, 12><<<gn, BK, 0, stream>>>(A, W2, dinv, B, n);                // g in B
  k_copy4<<<(n * 12 / 4 + BK - 1) / BK, BK, 0, stream>>>((const float4*)B, (float4*)A, n * 12 / 4);
  k_scatter<12><<<ge, BK, 0, stream>>>(srcI, dstI, B, A, e);                   // agg in A
  k_finalize<12, 1><<<gn, BK, 0, stream>>>(A, b2, dinv, B, n);                 // act2 in B

  // --- Layer 3: B[N,12] -> act3 in A[N,24], l2norm ---
  k_transform<12, 24><<<gn, BK, 0, stream>>>(B, W3, dinv, A, n);               // g in A
  k_copy4<<<(n * 24 / 4 + BK - 1) / BK, BK, 0, stream>>>((const float4*)A, (float4*)B, n * 24 / 4);
  k_scatter<24><<<ge, BK, 0, stream>>>(srcI, dstI, A, B, e);                   // agg in B
  k_finalize<24, 2><<<gn, BK, 0, stream>>>(B, b3, dinv, A, n);                 // act3 in A

  // --- Classifier: A[N,24] -> out[N,13], l2norm ---
  k_classifier<<<gn, BK, 0, stream>>>(A, Wc, bc, out, n);
}

// Round 2
// 1579.074 us; speedup vs baseline: 8.8484x; 8.8484x over previous
//
#include <hip/hip_runtime.h>
#include <math.h>

// GCN on MI355X. N=200000 nodes, E=6400000 edges.
// R2: replace push-style float atomics (4.8 GB HBM write-back churn) with
// CSR-by-dst build (counting sort) + pull-style register-accumulating gather.
// Per layer:  g[i] = dinv[i]*(act[i] @ W)
//             act'[d] = activation( dinv[d]*(g[d] + sum_{e:dst=d} g[src_e]) + b )

static constexpr int NN = 200000;
static constexpr int NE = 6400000;
static constexpr int BK = 256;
static constexpr int NB = (NN + BK - 1) / BK;  // 782 blocks for node-sized scans

// ---------- CSR build ----------
__global__ void k_zero(int* __restrict__ p, int n) {
  int i = blockIdx.x * blockDim.x + threadIdx.x;
  if (i < n) p[i] = 0;
}

__global__ void k_count(const int* __restrict__ dst, int* __restrict__ cnt, int e) {
  int i = blockIdx.x * blockDim.x + threadIdx.x;
  if (i < e) atomicAdd(cnt + dst[i], 1);
}

__global__ void k_dinv(const int* __restrict__ cnt, float* __restrict__ dinv, int n) {
  int i = blockIdx.x * blockDim.x + threadIdx.x;
  if (i < n) dinv[i] = rsqrtf(1.0f + (float)cnt[i]);  // +1 self-loop
}

__global__ void k_blocksum(const int* __restrict__ cnt, int* __restrict__ bsums, int n) {
  __shared__ int s[BK];
  int t = threadIdx.x;
  int i = blockIdx.x * BK + t;
  s[t] = (i < n) ? cnt[i] : 0;
  __syncthreads();
  for (int off = BK / 2; off > 0; off >>= 1) {
    if (t < off) s[t] += s[t + off];
    __syncthreads();
  }
  if (t == 0) bsums[blockIdx.x] = s[0];
}

// single block, 1024 threads: in-place exclusive scan of bsums[nb] (nb<=1024)
__global__ void k_scan_bsums(int* __restrict__ bsums, int nb) {
  __shared__ int s[1024];
  int t = threadIdx.x;
  int v = (t < nb) ? bsums[t] : 0;
  s[t] = v;
  __syncthreads();
  for (int off = 1; off < 1024; off <<= 1) {
    int x = (t >= off) ? s[t - off] : 0;
    __syncthreads();
    s[t] += x;
    __syncthreads();
  }
  if (t < nb) bsums[t] = s[t] - v;  // exclusive
}

__global__ void k_scan_final(const int* __restrict__ cnt, const int* __restrict__ bsums,
                             int* __restrict__ rowptr, int* __restrict__ cur, int n) {
  __shared__ int s[BK];
  int t = threadIdx.x;
  int i = blockIdx.x * BK + t;
  int v = (i < n) ? cnt[i] : 0;
  s[t] = v;
  __syncthreads();
  for (int off = 1; off < BK; off <<= 1) {
    int x = (t >= off) ? s[t - off] : 0;
    __syncthreads();
    s[t] += x;
    __syncthreads();
  }
  if (i < n) {
    int ex = bsums[blockIdx.x] + s[t] - v;
    rowptr[i] = ex;
    cur[i] = ex;
  }
}

__global__ void k_fill(const int* __restrict__ srcI, const int* __restrict__ dstI,
                       int* __restrict__ cur, int* __restrict__ adj, int e) {
  int i = blockIdx.x * blockDim.x + threadIdx.x;
  if (i < e) {
    int pos = atomicAdd(cur + dstI[i], 1);
    adj[pos] = srcI[i];
  }
}

// ---------- node transform: g[i] = dinv[i] * (act[i] @ W) ----------
template <int FIN, int FOUT>
__global__ void k_transform(const float* __restrict__ act, const float* __restrict__ W,
                            const float* __restrict__ dinv, float* __restrict__ g, int n) {
  __shared__ float sW[FIN * FOUT];
  for (int t = threadIdx.x; t < FIN * FOUT; t += blockDim.x) sW[t] = W[t];
  __syncthreads();
  int i = blockIdx.x * blockDim.x + threadIdx.x;
  if (i >= n) return;
  float a[FIN];
#pragma unroll
  for (int k = 0; k < FIN; ++k) a[k] = act[(size_t)i * FIN + k];
  float di = dinv[i];
#pragma unroll
  for (int j = 0; j < FOUT; ++j) {
    float s = 0.f;
#pragma unroll
    for (int k = 0; k < FIN; ++k) s = fmaf(a[k], sW[k * FOUT + j], s);
    g[(size_t)i * FOUT + j] = di * s;
  }
}

// ---------- pull gather + finalize ----------
template <int F>
__device__ inline void row_add(const float* __restrict__ row, float* __restrict__ acc) {
  if constexpr (F % 4 == 0) {
#pragma unroll
    for (int j = 0; j < F; j += 4) {
      float4 v = *(const float4*)(row + j);  // 16B-aligned for F=12,24
      acc[j] += v.x; acc[j + 1] += v.y; acc[j + 2] += v.z; acc[j + 3] += v.w;
    }
  } else {
#pragma unroll
    for (int j = 0; j < F; j += 2) {
      float2 v = *(const float2*)(row + j);  // F=6: 8B-aligned rows
      acc[j] += v.x; acc[j + 1] += v.y;
    }
  }
}

// MODE 0: tanh   MODE 1: l2norm then tanh   MODE 2: l2norm
template <int F, int MODE>
__global__ void k_gather(const int* __restrict__ adj, const int* __restrict__ rowptr,
                         const int* __restrict__ cnt, const float* __restrict__ g,
                         const float* __restrict__ b, const float* __restrict__ dinv,
                         float* __restrict__ out, int n) {
  int i = blockIdx.x * blockDim.x + threadIdx.x;
  if (i >= n) return;
  float acc[F] = {};
  row_add<F>(g + (size_t)i * F, acc);  // self-loop
  int st = rowptr[i];
  int c = cnt[i];
  for (int k = 0; k < c; ++k) {
    int s = adj[st + k];
    row_add<F>(g + (size_t)s * F, acc);
  }
  float di = dinv[i];
  float v[F];
  float ss = 0.f;
#pragma unroll
  for (int j = 0; j < F; ++j) {
    float t = fmaf(di, acc[j], b[j]);
    v[j] = t;
    ss += t * t;
  }
  if (MODE == 0) {
#pragma unroll
    for (int j = 0; j < F; ++j) v[j] = tanhf(v[j]);
  } else {
    float inv = 1.f / fmaxf(sqrtf(ss), 1e-12f);
#pragma unroll
    for (int j = 0; j < F; ++j) {
      float t = v[j] * inv;
      v[j] = (MODE == 1) ? tanhf(t) : t;
    }
  }
#pragma unroll
  for (int j = 0; j < F; ++j) out[(size_t)i * F + j] = v[j];
}

// ---------- classifier: out = l2norm(act @ Wc + bc) ----------
__global__ void k_classifier(const float* __restrict__ act, const float* __restrict__ Wc,
                             const float* __restrict__ bc, float* __restrict__ out, int n) {
  __shared__ float sW[24 * 13];
  __shared__ float sb[13];
  for (int t = threadIdx.x; t < 24 * 13; t += blockDim.x) sW[t] = Wc[t];
  if (threadIdx.x < 13) sb[threadIdx.x] = bc[threadIdx.x];
  __syncthreads();
  int i = blockIdx.x * blockDim.x + threadIdx.x;
  if (i >= n) return;
  float a[24];
#pragma unroll
  for (int k = 0; k < 24; ++k) a[k] = act[(size_t)i * 24 + k];
  float v[13];
  float ss = 0.f;
#pragma unroll
  for (int j = 0; j < 13; ++j) {
    float s = sb[j];
#pragma unroll
    for (int k = 0; k < 24; ++k) s = fmaf(a[k], sW[k * 13 + j], s);
    v[j] = s;
    ss += s * s;
  }
  float inv = 1.f / fmaxf(sqrtf(ss), 1e-12f);
#pragma unroll
  for (int j = 0; j < 13; ++j) out[(size_t)i * 13 + j] = v[j] * inv;
}

extern "C" void kernel_launch(void* const* d_in, const int* in_sizes, int n_in,
                              void* d_out, int out_size, void* d_ws, size_t ws_size,
                              hipStream_t stream) {
  const float* x  = (const float*)d_in[0];
  const int*   ei = (const int*)d_in[1];
  const float* W1 = (const float*)d_in[2];
  const float* b1 = (const float*)d_in[3];
  const float* W2 = (const float*)d_in[4];
  const float* b2 = (const float*)d_in[5];
  const float* W3 = (const float*)d_in[6];
  const float* b3 = (const float*)d_in[7];
  const float* Wc = (const float*)d_in[8];
  const float* bc = (const float*)d_in[9];
  float* out = (float*)d_out;

  const int n = NN;
  const int e = NE;
  const int* srcI = ei;       // row 0
  const int* dstI = ei + e;   // row 1

  // Workspace layout: dinv[N] f32 | A[N*24] f32 | B[N*24] f32 |
  //                   cnt[N] i32 | rowptr[N] i32 | cur[N] i32 | bsums[1024] i32 | adj[E] i32
  // total ~67.3 MB
  float* ws = (float*)d_ws;
  float* dinv = ws;
  float* A = ws + n;
  float* B = A + (size_t)n * 24;
  int* cnt    = (int*)(B + (size_t)n * 24);
  int* rowptr = cnt + n;
  int* cur    = rowptr + n;
  int* bsums  = cur + n;
  int* adj    = bsums + 1024;

  const int gn = (n + BK - 1) / BK;
  const int ge = (e + BK - 1) / BK;

  // --- CSR build (once; reused by all 3 layers) ---
  k_zero<<<gn, BK, 0, stream>>>(cnt, n);
  k_count<<<ge, BK, 0, stream>>>(dstI, cnt, e);
  k_dinv<<<gn, BK, 0, stream>>>(cnt, dinv, n);
  k_blocksum<<<NB, BK, 0, stream>>>(cnt, bsums, n);
  k_scan_bsums<<<1, 1024, 0, stream>>>(bsums, NB);
  k_scan_final<<<NB, BK, 0, stream>>>(cnt, bsums, rowptr, cur, n);
  k_fill<<<ge, BK, 0, stream>>>(srcI, dstI, cur, adj, e);

  // --- Layer 1: x[N,3] -> act1 in B[N,6], tanh ---
  k_transform<3, 6><<<gn, BK, 0, stream>>>(x, W1, dinv, A, n);
  k_gather<6, 0><<<gn, BK, 0, stream>>>(adj, rowptr, cnt, A, b1, dinv, B, n);

  // --- Layer 2: B[N,6] -> act2 in B[N,12], l2norm+tanh ---
  k_transform<6, 12><<<gn, BK, 0, stream>>>(B, W2, dinv, A, n);
  k_gather<12, 1><<<gn, BK, 0, stream>>>(adj, rowptr, cnt, A, b2, dinv, B, n);

  // --- Layer 3: B[N,12] -> act3 in B[N,24], l2norm ---
  k_transform<12, 24><<<gn, BK, 0, stream>>>(B, W3, dinv, A, n);
  k_gather<24, 2><<<gn, BK, 0, stream>>>(adj, rowptr, cnt, A, b3, dinv, B, n);

  // --- Classifier: B[N,24] -> out[N,13], l2norm ---
  k_classifier<<<gn, BK, 0, stream>>>(B, Wc, bc, out, n);
}

// Round 3
// 1352.130 us; speedup vs baseline: 10.3335x; 1.1678x over previous
//
#include <hip/hip_runtime.h>
#include <math.h>

// GCN on MI355X. N=200000 nodes, E=6400000 edges.
// R3: window the CSR fill by dst range so scattered adj writes stay L2-resident
// (R2's k_fill showed 392 MB WRITE_SIZE for a 25.6 MB array = 15x churn).
// Edge list is L3-resident after k_count, so 16x re-read is cheap.

static constexpr int NN = 200000;
static constexpr int NE = 6400000;
static constexpr int BK = 256;
static constexpr int NB = (NN + BK - 1) / BK;   // node-sized scan blocks
static constexpr int NWIN = 16;                 // fill windows
static constexpr int WINSZ = (NN + NWIN - 1) / NWIN;  // 12500 nodes -> 1.6 MB adj/window

// ---------- CSR build ----------
__global__ void k_zero(int* __restrict__ p, int n) {
  int i = blockIdx.x * blockDim.x + threadIdx.x;
  if (i < n) p[i] = 0;
}

__global__ void k_count(const int* __restrict__ dst, int* __restrict__ cnt, int e) {
  int i = blockIdx.x * blockDim.x + threadIdx.x;
  if (i < e) atomicAdd(cnt + dst[i], 1);
}

__global__ void k_dinv(const int* __restrict__ cnt, float* __restrict__ dinv, int n) {
  int i = blockIdx.x * blockDim.x + threadIdx.x;
  if (i < n) dinv[i] = rsqrtf(1.0f + (float)cnt[i]);  // +1 self-loop
}

__global__ void k_blocksum(const int* __restrict__ cnt, int* __restrict__ bsums, int n) {
  __shared__ int s[BK];
  int t = threadIdx.x;
  int i = blockIdx.x * BK + t;
  s[t] = (i < n) ? cnt[i] : 0;
  __syncthreads();
  for (int off = BK / 2; off > 0; off >>= 1) {
    if (t < off) s[t] += s[t + off];
    __syncthreads();
  }
  if (t == 0) bsums[blockIdx.x] = s[0];
}

// single block, 1024 threads: in-place exclusive scan of bsums[nb] (nb<=1024)
__global__ void k_scan_bsums(int* __restrict__ bsums, int nb) {
  __shared__ int s[1024];
  int t = threadIdx.x;
  int v = (t < nb) ? bsums[t] : 0;
  s[t] = v;
  __syncthreads();
  for (int off = 1; off < 1024; off <<= 1) {
    int x = (t >= off) ? s[t - off] : 0;
    __syncthreads();
    s[t] += x;
    __syncthreads();
  }
  if (t < nb) bsums[t] = s[t] - v;  // exclusive
}

__global__ void k_scan_final(const int* __restrict__ cnt, const int* __restrict__ bsums,
                             int* __restrict__ rowptr, int* __restrict__ cur, int n) {
  __shared__ int s[BK];
  int t = threadIdx.x;
  int i = blockIdx.x * BK + t;
  int v = (i < n) ? cnt[i] : 0;
  s[t] = v;
  __syncthreads();
  for (int off = 1; off < BK; off <<= 1) {
    int x = (t >= off) ? s[t - off] : 0;
    __syncthreads();
    s[t] += x;
    __syncthreads();
  }
  if (i < n) {
    int ex = bsums[blockIdx.x] + s[t] - v;
    rowptr[i] = ex;
    cur[i] = ex;
  }
}

// Windowed fill: blocks with blockIdx.y==w only handle dst in [w*WINSZ,(w+1)*WINSZ).
// Scattered adj writes stay within a ~1.6 MB region -> L2-resident, single writeback.
__global__ void k_fill_win(const int* __restrict__ srcI, const int* __restrict__ dstI,
                           int* __restrict__ cur, int* __restrict__ adj, int e) {
  int lo = blockIdx.y * WINSZ;
  int hi = lo + WINSZ;
  int stride = gridDim.x * blockDim.x;
  for (int i = blockIdx.x * blockDim.x + threadIdx.x; i < e; i += stride) {
    int d = dstI[i];
    if (d >= lo && d < hi) {
      int pos = atomicAdd(cur + d, 1);
      adj[pos] = srcI[i];
    }
  }
}

// ---------- node transform: g[i] = dinv[i] * (act[i] @ W) ----------
template <int FIN, int FOUT>
__global__ void k_transform(const float* __restrict__ act, const float* __restrict__ W,
                            const float* __restrict__ dinv, float* __restrict__ g, int n) {
  __shared__ float sW[FIN * FOUT];
  for (int t = threadIdx.x; t < FIN * FOUT; t += blockDim.x) sW[t] = W[t];
  __syncthreads();
  int i = blockIdx.x * blockDim.x + threadIdx.x;
  if (i >= n) return;
  float a[FIN];
#pragma unroll
  for (int k = 0; k < FIN; ++k) a[k] = act[(size_t)i * FIN + k];
  float di = dinv[i];
#pragma unroll
  for (int j = 0; j < FOUT; ++j) {
    float s = 0.f;
#pragma unroll
    for (int k = 0; k < FIN; ++k) s = fmaf(a[k], sW[k * FOUT + j], s);
    g[(size_t)i * FOUT + j] = di * s;
  }
}

// ---------- pull gather + finalize ----------
template <int F>
__device__ inline void row_add(const float* __restrict__ row, float* __restrict__ acc) {
  if constexpr (F % 4 == 0) {
#pragma unroll
    for (int j = 0; j < F; j += 4) {
      float4 v = *(const float4*)(row + j);  // 16B-aligned for F=12,24
      acc[j] += v.x; acc[j + 1] += v.y; acc[j + 2] += v.z; acc[j + 3] += v.w;
    }
  } else {
#pragma unroll
    for (int j = 0; j < F; j += 2) {
      float2 v = *(const float2*)(row + j);  // F=6: 8B-aligned rows
      acc[j] += v.x; acc[j + 1] += v.y;
    }
  }
}

// MODE 0: tanh   MODE 1: l2norm then tanh   MODE 2: l2norm
template <int F, int MODE>
__global__ void k_gather(const int* __restrict__ adj, const int* __restrict__ rowptr,
                         const int* __restrict__ cnt, const float* __restrict__ g,
                         const float* __restrict__ b, const float* __restrict__ dinv,
                         float* __restrict__ out, int n) {
  int i = blockIdx.x * blockDim.x + threadIdx.x;
  if (i >= n) return;
  float acc[F] = {};
  row_add<F>(g + (size_t)i * F, acc);  // self-loop
  int st = rowptr[i];
  int c = cnt[i];
  for (int k = 0; k < c; ++k) {
    int s = adj[st + k];
    row_add<F>(g + (size_t)s * F, acc);
  }
  float di = dinv[i];
  float v[F];
  float ss = 0.f;
#pragma unroll
  for (int j = 0; j < F; ++j) {
    float t = fmaf(di, acc[j], b[j]);
    v[j] = t;
    ss += t * t;
  }
  if (MODE == 0) {
#pragma unroll
    for (int j = 0; j < F; ++j) v[j] = tanhf(v[j]);
  } else {
    float inv = 1.f / fmaxf(sqrtf(ss), 1e-12f);
#pragma unroll
    for (int j = 0; j < F; ++j) {
      float t = v[j] * inv;
      v[j] = (MODE == 1) ? tanhf(t) : t;
    }
  }
#pragma unroll
  for (int j = 0; j < F; ++j) out[(size_t)i * F + j] = v[j];
}

// ---------- classifier: out = l2norm(act @ Wc + bc) ----------
__global__ void k_classifier(const float* __restrict__ act, const float* __restrict__ Wc,
                             const float* __restrict__ bc, float* __restrict__ out, int n) {
  __shared__ float sW[24 * 13];
  __shared__ float sb[13];
  for (int t = threadIdx.x; t < 24 * 13; t += blockDim.x) sW[t] = Wc[t];
  if (threadIdx.x < 13) sb[threadIdx.x] = bc[threadIdx.x];
  __syncthreads();
  int i = blockIdx.x * blockDim.x + threadIdx.x;
  if (i >= n) return;
  float a[24];
#pragma unroll
  for (int k = 0; k < 24; ++k) a[k] = act[(size_t)i * 24 + k];
  float v[13];
  float ss = 0.f;
#pragma unroll
  for (int j = 0; j < 13; ++j) {
    float s = sb[j];
#pragma unroll
    for (int k = 0; k < 24; ++k) s = fmaf(a[k], sW[k * 13 + j], s);
    v[j] = s;
    ss += s * s;
  }
  float inv = 1.f / fmaxf(sqrtf(ss), 1e-12f);
#pragma unroll
  for (int j = 0; j < 13; ++j) out[(size_t)i * 13 + j] = v[j] * inv;
}

extern "C" void kernel_launch(void* const* d_in, const int* in_sizes, int n_in,
                              void* d_out, int out_size, void* d_ws, size_t ws_size,
                              hipStream_t stream) {
  const float* x  = (const float*)d_in[0];
  const int*   ei = (const int*)d_in[1];
  const float* W1 = (const float*)d_in[2];
  const float* b1 = (const float*)d_in[3];
  const float* W2 = (const float*)d_in[4];
  const float* b2 = (const float*)d_in[5];
  const float* W3 = (const float*)d_in[6];
  const float* b3 = (const float*)d_in[7];
  const float* Wc = (const float*)d_in[8];
  const float* bc = (const float*)d_in[9];
  float* out = (float*)d_out;

  const int n = NN;
  const int e = NE;
  const int* srcI = ei;       // row 0
  const int* dstI = ei + e;   // row 1

  // Workspace layout: dinv[N] f32 | A[N*24] f32 | B[N*24] f32 |
  //                   cnt[N] i32 | rowptr[N] i32 | cur[N] i32 | bsums[1024] i32 | adj[E] i32
  // total ~67.3 MB
  float* ws = (float*)d_ws;
  float* dinv = ws;
  float* A = ws + n;
  float* B = A + (size_t)n * 24;
  int* cnt    = (int*)(B + (size_t)n * 24);
  int* rowptr = cnt + n;
  int* cur    = rowptr + n;
  int* bsums  = cur + n;
  int* adj    = bsums + 1024;

  const int gn = (n + BK - 1) / BK;
  const int ge = (e + BK - 1) / BK;

  // --- CSR build (once; reused by all 3 layers) ---
  k_zero<<<gn, BK, 0, stream>>>(cnt, n);
  k_count<<<ge, BK, 0, stream>>>(dstI, cnt, e);       // also warms edge list into L3
  k_dinv<<<gn, BK, 0, stream>>>(cnt, dinv, n);
  k_blocksum<<<NB, BK, 0, stream>>>(cnt, bsums, n);
  k_scan_bsums<<<1, 1024, 0, stream>>>(bsums, NB);
  k_scan_final<<<NB, BK, 0, stream>>>(cnt, bsums, rowptr, cur, n);
  k_fill_win<<<dim3(1024, NWIN), BK, 0, stream>>>(srcI, dstI, cur, adj, e);

  // --- Layer 1: x[N,3] -> act1 in B[N,6], tanh ---
  k_transform<3, 6><<<gn, BK, 0, stream>>>(x, W1, dinv, A, n);
  k_gather<6, 0><<<gn, BK, 0, stream>>>(adj, rowptr, cnt, A, b1, dinv, B, n);

  // --- Layer 2: B[N,6] -> act2 in B[N,12], l2norm+tanh ---
  k_transform<6, 12><<<gn, BK, 0, stream>>>(B, W2, dinv, A, n);
  k_gather<12, 1><<<gn, BK, 0, stream>>>(adj, rowptr, cnt, A, b2, dinv, B, n);

  // --- Layer 3: B[N,12] -> act3 in B[N,24], l2norm ---
  k_transform<12, 24><<<gn, BK, 0, stream>>>(B, W3, dinv, A, n);
  k_gather<24, 2><<<gn, BK, 0, stream>>>(adj, rowptr, cnt, A, b3, dinv, B, n);

  // --- Classifier: B[N,24] -> out[N,13], l2norm ---
  k_classifier<<<gn, BK, 0, stream>>>(B, Wc, bc, out, n);
}

// Round 4
// 1327.846 us; speedup vs baseline: 10.5225x; 1.0183x over previous
//
#include <hip/hip_runtime.h>
#include <math.h>

// GCN on MI355X. N=200000 nodes, E=6400000 edges.
// R4: XCD-affine windowed CSR build. R3 showed the adj write amplification
// (397 MB for 25.6 MB) is CROSS-XCD false sharing: a window's adj lines were
// dirtied in all 8 per-XCD L2s. Now window w is processed only by blocks with
// blockIdx%8==w (round-robin XCD dispatch heuristic), so each adj/cnt/cur line
// is owned by exactly one L2. Edge-stream reads are nontemporal so they don't
// evict the dirty scatter lines (still L3-served).

static constexpr int NN = 200000;
static constexpr int NE = 6400000;
static constexpr int BK = 256;
static constexpr int NB = (NN + BK - 1) / BK;   // node-sized scan blocks
static constexpr int NWIN = 8;                  // one window per XCD
static constexpr int WINSZ = NN / NWIN;         // 25000 nodes
static constexpr int BPW = 256;                 // blocks per window (per XCD: 32 CUs)

// ---------- CSR build ----------
__global__ void k_zero(int* __restrict__ p, int n) {
  int i = blockIdx.x * blockDim.x + threadIdx.x;
  if (i < n) p[i] = 0;
}

// XCD-affine windowed count: blocks with blockIdx%8==w count only dst in window w.
__global__ void k_count_x(const int* __restrict__ dstI, int* __restrict__ cnt, int e) {
  int b = blockIdx.x;
  int w = b & (NWIN - 1);       // window == assumed XCD id
  int slot = b >> 3;            // 0..BPW-1 within window
  int lo = w * WINSZ;
  int hi = lo + WINSZ;
  int stride = BPW * BK;
  for (int i = slot * BK + (int)threadIdx.x; i < e; i += stride) {
    int d = __builtin_nontemporal_load(dstI + i);
    if (d >= lo && d < hi) atomicAdd(cnt + d, 1);
  }
}

__global__ void k_dinv(const int* __restrict__ cnt, float* __restrict__ dinv, int n) {
  int i = blockIdx.x * blockDim.x + threadIdx.x;
  if (i < n) dinv[i] = rsqrtf(1.0f + (float)cnt[i]);  // +1 self-loop
}

__global__ void k_blocksum(const int* __restrict__ cnt, int* __restrict__ bsums, int n) {
  __shared__ int s[BK];
  int t = threadIdx.x;
  int i = blockIdx.x * BK + t;
  s[t] = (i < n) ? cnt[i] : 0;
  __syncthreads();
  for (int off = BK / 2; off > 0; off >>= 1) {
    if (t < off) s[t] += s[t + off];
    __syncthreads();
  }
  if (t == 0) bsums[blockIdx.x] = s[0];
}

// single block, 1024 threads: in-place exclusive scan of bsums[nb] (nb<=1024)
__global__ void k_scan_bsums(int* __restrict__ bsums, int nb) {
  __shared__ int s[1024];
  int t = threadIdx.x;
  int v = (t < nb) ? bsums[t] : 0;
  s[t] = v;
  __syncthreads();
  for (int off = 1; off < 1024; off <<= 1) {
    int x = (t >= off) ? s[t - off] : 0;
    __syncthreads();
    s[t] += x;
    __syncthreads();
  }
  if (t < nb) bsums[t] = s[t] - v;  // exclusive
}

__global__ void k_scan_final(const int* __restrict__ cnt, const int* __restrict__ bsums,
                             int* __restrict__ rowptr, int* __restrict__ cur, int n) {
  __shared__ int s[BK];
  int t = threadIdx.x;
  int i = blockIdx.x * BK + t;
  int v = (i < n) ? cnt[i] : 0;
  s[t] = v;
  __syncthreads();
  for (int off = 1; off < BK; off <<= 1) {
    int x = (t >= off) ? s[t - off] : 0;
    __syncthreads();
    s[t] += x;
    __syncthreads();
  }
  if (i < n) {
    int ex = bsums[blockIdx.x] + s[t] - v;
    rowptr[i] = ex;
    cur[i] = ex;
  }
}

// XCD-affine windowed fill: window w's adj region (~3.2 MB) + cur slice (100 KB)
// are written only from XCD w -> single-L2 ownership, one writeback per line.
__global__ void k_fill_x(const int* __restrict__ srcI, const int* __restrict__ dstI,
                         int* __restrict__ cur, int* __restrict__ adj, int e) {
  int b = blockIdx.x;
  int w = b & (NWIN - 1);
  int slot = b >> 3;
  int lo = w * WINSZ;
  int hi = lo + WINSZ;
  int stride = BPW * BK;
  for (int i = slot * BK + (int)threadIdx.x; i < e; i += stride) {
    int d = __builtin_nontemporal_load(dstI + i);
    if (d >= lo && d < hi) {
      int s = __builtin_nontemporal_load(srcI + i);
      int pos = atomicAdd(cur + d, 1);
      adj[pos] = s;
    }
  }
}

// ---------- node transform: g[i] = dinv[i] * (act[i] @ W) ----------
template <int FIN, int FOUT>
__global__ void k_transform(const float* __restrict__ act, const float* __restrict__ W,
                            const float* __restrict__ dinv, float* __restrict__ g, int n) {
  __shared__ float sW[FIN * FOUT];
  for (int t = threadIdx.x; t < FIN * FOUT; t += blockDim.x) sW[t] = W[t];
  __syncthreads();
  int i = blockIdx.x * blockDim.x + threadIdx.x;
  if (i >= n) return;
  float a[FIN];
#pragma unroll
  for (int k = 0; k < FIN; ++k) a[k] = act[(size_t)i * FIN + k];
  float di = dinv[i];
#pragma unroll
  for (int j = 0; j < FOUT; ++j) {
    float s = 0.f;
#pragma unroll
    for (int k = 0; k < FIN; ++k) s = fmaf(a[k], sW[k * FOUT + j], s);
    g[(size_t)i * FOUT + j] = di * s;
  }
}

// ---------- pull gather + finalize ----------
template <int F>
__device__ inline void row_add(const float* __restrict__ row, float* __restrict__ acc) {
  if constexpr (F % 4 == 0) {
#pragma unroll
    for (int j = 0; j < F; j += 4) {
      float4 v = *(const float4*)(row + j);  // 16B-aligned for F=12,24
      acc[j] += v.x; acc[j + 1] += v.y; acc[j + 2] += v.z; acc[j + 3] += v.w;
    }
  } else {
#pragma unroll
    for (int j = 0; j < F; j += 2) {
      float2 v = *(const float2*)(row + j);  // F=6: 8B-aligned rows
      acc[j] += v.x; acc[j + 1] += v.y;
    }
  }
}

// MODE 0: tanh   MODE 1: l2norm then tanh   MODE 2: l2norm
template <int F, int MODE>
__global__ void k_gather(const int* __restrict__ adj, const int* __restrict__ rowptr,
                         const int* __restrict__ cnt, const float* __restrict__ g,
                         const float* __restrict__ b, const float* __restrict__ dinv,
                         float* __restrict__ out, int n) {
  int i = blockIdx.x * blockDim.x + threadIdx.x;
  if (i >= n) return;
  float acc[F] = {};
  row_add<F>(g + (size_t)i * F, acc);  // self-loop
  int st = rowptr[i];
  int c = cnt[i];
  for (int k = 0; k < c; ++k) {
    int s = adj[st + k];
    row_add<F>(g + (size_t)s * F, acc);
  }
  float di = dinv[i];
  float v[F];
  float ss = 0.f;
#pragma unroll
  for (int j = 0; j < F; ++j) {
    float t = fmaf(di, acc[j], b[j]);
    v[j] = t;
    ss += t * t;
  }
  if (MODE == 0) {
#pragma unroll
    for (int j = 0; j < F; ++j) v[j] = tanhf(v[j]);
  } else {
    float inv = 1.f / fmaxf(sqrtf(ss), 1e-12f);
#pragma unroll
    for (int j = 0; j < F; ++j) {
      float t = v[j] * inv;
      v[j] = (MODE == 1) ? tanhf(t) : t;
    }
  }
#pragma unroll
  for (int j = 0; j < F; ++j) out[(size_t)i * F + j] = v[j];
}

// ---------- classifier: out = l2norm(act @ Wc + bc) ----------
__global__ void k_classifier(const float* __restrict__ act, const float* __restrict__ Wc,
                             const float* __restrict__ bc, float* __restrict__ out, int n) {
  __shared__ float sW[24 * 13];
  __shared__ float sb[13];
  for (int t = threadIdx.x; t < 24 * 13; t += blockDim.x) sW[t] = Wc[t];
  if (threadIdx.x < 13) sb[threadIdx.x] = bc[threadIdx.x];
  __syncthreads();
  int i = blockIdx.x * blockDim.x + threadIdx.x;
  if (i >= n) return;
  float a[24];
#pragma unroll
  for (int k = 0; k < 24; ++k) a[k] = act[(size_t)i * 24 + k];
  float v[13];
  float ss = 0.f;
#pragma unroll
  for (int j = 0; j < 13; ++j) {
    float s = sb[j];
#pragma unroll
    for (int k = 0; k < 24; ++k) s = fmaf(a[k], sW[k * 13 + j], s);
    v[j] = s;
    ss += s * s;
  }
  float inv = 1.f / fmaxf(sqrtf(ss), 1e-12f);
#pragma unroll
  for (int j = 0; j < 13; ++j) out[(size_t)i * 13 + j] = v[j] * inv;
}

extern "C" void kernel_launch(void* const* d_in, const int* in_sizes, int n_in,
                              void* d_out, int out_size, void* d_ws, size_t ws_size,
                              hipStream_t stream) {
  const float* x  = (const float*)d_in[0];
  const int*   ei = (const int*)d_in[1];
  const float* W1 = (const float*)d_in[2];
  const float* b1 = (const float*)d_in[3];
  const float* W2 = (const float*)d_in[4];
  const float* b2 = (const float*)d_in[5];
  const float* W3 = (const float*)d_in[6];
  const float* b3 = (const float*)d_in[7];
  const float* Wc = (const float*)d_in[8];
  const float* bc = (const float*)d_in[9];
  float* out = (float*)d_out;

  const int n = NN;
  const int e = NE;
  const int* srcI = ei;       // row 0
  const int* dstI = ei + e;   // row 1

  // Workspace layout: dinv[N] f32 | A[N*24] f32 | B[N*24] f32 |
  //                   cnt[N] i32 | rowptr[N] i32 | cur[N] i32 | bsums[1024] i32 | adj[E] i32
  // total ~67.3 MB
  float* ws = (float*)d_ws;
  float* dinv = ws;
  float* A = ws + n;
  float* B = A + (size_t)n * 24;
  int* cnt    = (int*)(B + (size_t)n * 24);
  int* rowptr = cnt + n;
  int* cur    = rowptr + n;
  int* bsums  = cur + n;
  int* adj    = bsums + 1024;

  const int gn = (n + BK - 1) / BK;

  // --- CSR build (once; reused by all 3 layers) ---
  k_zero<<<gn, BK, 0, stream>>>(cnt, n);
  k_count_x<<<NWIN * BPW, BK, 0, stream>>>(dstI, cnt, e);
  k_dinv<<<gn, BK, 0, stream>>>(cnt, dinv, n);
  k_blocksum<<<NB, BK, 0, stream>>>(cnt, bsums, n);
  k_scan_bsums<<<1, 1024, 0, stream>>>(bsums, NB);
  k_scan_final<<<NB, BK, 0, stream>>>(cnt, bsums, rowptr, cur, n);
  k_fill_x<<<NWIN * BPW, BK, 0, stream>>>(srcI, dstI, cur, adj, e);

  // --- Layer 1: x[N,3] -> act1 in B[N,6], tanh ---
  k_transform<3, 6><<<gn, BK, 0, stream>>>(x, W1, dinv, A, n);
  k_gather<6, 0><<<gn, BK, 0, stream>>>(adj, rowptr, cnt, A, b1, dinv, B, n);

  // --- Layer 2: B[N,6] -> act2 in B[N,12], l2norm+tanh ---
  k_transform<6, 12><<<gn, BK, 0, stream>>>(B, W2, dinv, A, n);
  k_gather<12, 1><<<gn, BK, 0, stream>>>(adj, rowptr, cnt, A, b2, dinv, B, n);

  // --- Layer 3: B[N,12] -> act3 in B[N,24], l2norm ---
  k_transform<12, 24><<<gn, BK, 0, stream>>>(B, W3, dinv, A, n);
  k_gather<24, 2><<<gn, BK, 0, stream>>>(adj, rowptr, cnt, A, b3, dinv, B, n);

  // --- Classifier: B[N,24] -> out[N,13], l2norm ---
  k_classifier<<<gn, BK, 0, stream>>>(B, Wc, bc, out, n);
}

// Round 8
// 1055.910 us; speedup vs baseline: 13.2325x; 1.2575x over previous
//
#include <hip/hip_runtime.h>
#include <math.h>

// GCN on MI355X. N=200000 nodes, E=6400000 edges.
// R8: R7's bisect proved the 0.2097 failures were the bf16 MESSAGE PATH
// (deterministic quantization amplified by intermediate l2_normalize), NOT the
// counting sort (same build as passing R4 + bf16 = same exact error as R5/R6).
// So: fp32 messages (proven R2-R4, absmax 0.0039) + LDS-binned counting-sort
// CSR build (exonerated; each staging/adj line written ~once vs 400 MB
// writeback churn of R4's atomic count + windowed fill).
// MESSAGES MUST STAY FP32: bf16 messages fail at 0.21 via small-norm l2norm
// amplification -- do not retry reduced precision here.

static constexpr int NN = 200000;
static constexpr int NE = 6400000;
static constexpr int BK = 256;

static constexpr int SUBW  = 512;                    // nodes per sub-bin (pow2)
static constexpr int NBA   = (NN + SUBW - 1) / SUBW; // 391 sub-bins
static constexpr int CAP   = 32;                     // LDS bin capacity (recs)
static constexpr int FLUSH = 16;                     // flush granule = 64B
static constexpr int CAPB  = 18400;                  // per-bin staging cap (mean 16384, sd 128 -> +15.7 sigma); %16==0; NBA*CAPB <= N*36
static constexpr int GPART = 768;                    // k_part grid (50.4KB LDS -> 3 blocks/CU)

// ---------- pass 1: LDS-binned partition of edges into per-sub-bin staging ----------
__global__ void __launch_bounds__(BK) k_part(const int* __restrict__ srcI,
                                             const int* __restrict__ dstI,
                                             unsigned* __restrict__ stg,
                                             int* __restrict__ gtail, int e) {
  __shared__ unsigned bin[CAP][NBA];   // [slot][bin]: random-bin writes spread banks
  __shared__ int bcnt[NBA];
  for (int t = threadIdx.x; t < NBA; t += BK) bcnt[t] = 0;
  __syncthreads();
  int nchunks = (e + BK - 1) / BK;
  for (int c = blockIdx.x; c < nchunks; c += gridDim.x) {
    int i = c * BK + (int)threadIdx.x;
    if (i < e) {
      int d = __builtin_nontemporal_load(dstI + i);
      int s = __builtin_nontemporal_load(srcI + i);
      int b = d >> 9;                                        // sub-bin
      unsigned rec = ((unsigned)(d & (SUBW - 1)) << 18) | (unsigned)s;  // src < 2^18
      int p = atomicAdd(&bcnt[b], 1);
      if (p < CAP) {
        bin[p][b] = rec;
      } else {
        // overflow fallback (rare): reserve one staging slot directly
        int base = atomicAdd(&gtail[b], 1);
        stg[(size_t)b * CAPB + base] = rec;
      }
    }
    __syncthreads();
    // flush full 16-record (64B) chunks; stored recs = min(bcnt, CAP)
    for (int b2 = threadIdx.x; b2 < NBA; b2 += BK) {
      int c2 = bcnt[b2];
      if (c2 > CAP) c2 = CAP;
      if (c2 >= FLUSH) {
        int nfl = c2 & ~(FLUSH - 1);
        int base = atomicAdd(&gtail[b2], nfl);
        size_t o = (size_t)b2 * CAPB + base;
        for (int k = 0; k < nfl; ++k) stg[o + k] = bin[k][b2];
        int r = c2 - nfl;
        for (int k = 0; k < r; ++k) bin[k][b2] = bin[nfl + k][b2];
        bcnt[b2] = r;
      }
    }
    __syncthreads();
  }
  // final flush of residuals
  for (int b2 = threadIdx.x; b2 < NBA; b2 += BK) {
    int c2 = bcnt[b2];
    if (c2 > CAP) c2 = CAP;
    if (c2 > 0) {
      int base = atomicAdd(&gtail[b2], c2);
      size_t o = (size_t)b2 * CAPB + base;
      for (int k = 0; k < c2; ++k) stg[o + k] = bin[k][b2];
    }
  }
}

// ---------- exclusive scan over 391 sub-bin sizes (single block) ----------
__global__ void k_scan_sub(const int* __restrict__ gtail, int* __restrict__ sbase) {
  __shared__ int s0[512], s1[512];
  int t = threadIdx.x;
  int v = (t < NBA) ? gtail[t] : 0;
  s0[t] = v;
  __syncthreads();
  int* a = s0; int* b = s1;
  for (int off = 1; off < 512; off <<= 1) {
    int x = a[t] + ((t >= off) ? a[t - off] : 0);
    b[t] = x;
    __syncthreads();
    int* tmp = a; a = b; b = tmp;
  }
  if (t < NBA) sbase[t] = a[t] - v;  // exclusive
}

// ---------- pass 2: per-sub-bin hist + scan + scatter -> cnt, rowptr, adj ----------
__global__ void __launch_bounds__(BK) k_build(const unsigned* __restrict__ stg,
                                              const int* __restrict__ gtail,
                                              const int* __restrict__ sbase,
                                              int* __restrict__ cnt,
                                              int* __restrict__ rowptr,
                                              int* __restrict__ adj) {
  __shared__ int hist[SUBW];
  __shared__ int s0[SUBW], s1[SUBW];
  int b = blockIdx.x;
  int m = gtail[b]; if (m > CAPB) m = CAPB;
  size_t off = (size_t)b * CAPB;
  int base = sbase[b];
  for (int t = threadIdx.x; t < SUBW; t += BK) hist[t] = 0;
  __syncthreads();
  for (int k = threadIdx.x; k < m; k += BK) atomicAdd(&hist[stg[off + k] >> 18], 1);
  __syncthreads();
  for (int t = threadIdx.x; t < SUBW; t += BK) s0[t] = hist[t];
  __syncthreads();
  int* a = s0; int* bb = s1;
  for (int o2 = 1; o2 < SUBW; o2 <<= 1) {
    for (int t = threadIdx.x; t < SUBW; t += BK) bb[t] = a[t] + ((t >= o2) ? a[t - o2] : 0);
    __syncthreads();
    int* tmp = a; a = bb; bb = tmp;
  }
  for (int t = threadIdx.x; t < SUBW; t += BK) {
    int node = b * SUBW + t;
    int ex = a[t] - hist[t];
    if (node < NN) { cnt[node] = hist[t]; rowptr[node] = base + ex; }
    bb[t] = ex;  // cur init in the free buffer
  }
  __syncthreads();
  int* cur = bb;
  for (int k = threadIdx.x; k < m; k += BK) {
    unsigned rec = stg[off + k];
    int dl = rec >> 18;
    int p = atomicAdd(&cur[dl], 1);
    adj[base + p] = (int)(rec & 0x3FFFFu);  // single-block 64KB region: L2-resident
  }
}

__global__ void k_zero(int* __restrict__ p, int n) {
  int i = blockIdx.x * blockDim.x + threadIdx.x;
  if (i < n) p[i] = 0;
}

__global__ void k_dinv(const int* __restrict__ cnt, float* __restrict__ dinv, int n) {
  int i = blockIdx.x * blockDim.x + threadIdx.x;
  if (i < n) dinv[i] = rsqrtf(1.0f + (float)cnt[i]);  // +1 self-loop
}

// ---------- node transform: g[i] = dinv[i] * (act[i] @ W), fp32 ----------
template <int FIN, int FOUT>
__global__ void k_transform(const float* __restrict__ act, const float* __restrict__ W,
                            const float* __restrict__ dinv, float* __restrict__ g, int n) {
  __shared__ float sW[FIN * FOUT];
  for (int t = threadIdx.x; t < FIN * FOUT; t += blockDim.x) sW[t] = W[t];
  __syncthreads();
  int i = blockIdx.x * blockDim.x + threadIdx.x;
  if (i >= n) return;
  float a[FIN];
#pragma unroll
  for (int k = 0; k < FIN; ++k) a[k] = act[(size_t)i * FIN + k];
  float di = dinv[i];
#pragma unroll
  for (int j = 0; j < FOUT; ++j) {
    float s = 0.f;
#pragma unroll
    for (int k = 0; k < FIN; ++k) s = fmaf(a[k], sW[k * FOUT + j], s);
    g[(size_t)i * FOUT + j] = di * s;
  }
}

// ---------- fp32 row accumulate ----------
template <int F>
__device__ inline void row_add(const float* __restrict__ row, float* __restrict__ acc) {
  if constexpr (F % 4 == 0) {
#pragma unroll
    for (int j = 0; j < F; j += 4) {
      float4 v = *(const float4*)(row + j);  // 16B-aligned for F=12,24
      acc[j] += v.x; acc[j + 1] += v.y; acc[j + 2] += v.z; acc[j + 3] += v.w;
    }
  } else {
#pragma unroll
    for (int j = 0; j < F; j += 2) {
      float2 v = *(const float2*)(row + j);  // F=6: 8B-aligned rows
      acc[j] += v.x; acc[j + 1] += v.y;
    }
  }
}

// MODE 0: tanh   MODE 1: l2norm then tanh   MODE 2: l2norm
template <int F, int MODE>
__global__ void k_gather(const int* __restrict__ adj, const int* __restrict__ rowptr,
                         const int* __restrict__ cnt, const float* __restrict__ g,
                         const float* __restrict__ b, const float* __restrict__ dinv,
                         float* __restrict__ out, int n) {
  int i = blockIdx.x * blockDim.x + threadIdx.x;
  if (i >= n) return;
  float acc[F] = {};
  row_add<F>(g + (size_t)i * F, acc);  // self-loop
  int st = rowptr[i];
  int c = cnt[i];
  for (int k = 0; k < c; ++k) {
    int s = adj[st + k];
    row_add<F>(g + (size_t)s * F, acc);
  }
  float di = dinv[i];
  float v[F];
  float ss = 0.f;
#pragma unroll
  for (int j = 0; j < F; ++j) {
    float t = fmaf(di, acc[j], b[j]);
    v[j] = t;
    ss += t * t;
  }
  if (MODE == 0) {
#pragma unroll
    for (int j = 0; j < F; ++j) v[j] = tanhf(v[j]);
  } else {
    float inv = 1.f / fmaxf(sqrtf(ss), 1e-12f);
#pragma unroll
    for (int j = 0; j < F; ++j) {
      float t = v[j] * inv;
      v[j] = (MODE == 1) ? tanhf(t) : t;
    }
  }
#pragma unroll
  for (int j = 0; j < F; ++j) out[(size_t)i * F + j] = v[j];
}

// ---------- classifier: out = l2norm(act @ Wc + bc) ----------
__global__ void k_classifier(const float* __restrict__ act, const float* __restrict__ Wc,
                             const float* __restrict__ bc, float* __restrict__ out, int n) {
  __shared__ float sW[24 * 13];
  __shared__ float sb[13];
  for (int t = threadIdx.x; t < 24 * 13; t += blockDim.x) sW[t] = Wc[t];
  if (threadIdx.x < 13) sb[threadIdx.x] = bc[threadIdx.x];
  __syncthreads();
  int i = blockIdx.x * blockDim.x + threadIdx.x;
  if (i >= n) return;
  float a[24];
#pragma unroll
  for (int k = 0; k < 24; ++k) a[k] = act[(size_t)i * 24 + k];
  float v[13];
  float ss = 0.f;
#pragma unroll
  for (int j = 0; j < 13; ++j) {
    float s = sb[j];
#pragma unroll
    for (int k = 0; k < 24; ++k) s = fmaf(a[k], sW[k * 13 + j], s);
    v[j] = s;
    ss += s * s;
  }
  float inv = 1.f / fmaxf(sqrtf(ss), 1e-12f);
#pragma unroll
  for (int j = 0; j < 13; ++j) out[(size_t)i * 13 + j] = v[j] * inv;
}

extern "C" void kernel_launch(void* const* d_in, const int* in_sizes, int n_in,
                              void* d_out, int out_size, void* d_ws, size_t ws_size,
                              hipStream_t stream) {
  const float* x  = (const float*)d_in[0];
  const int*   ei = (const int*)d_in[1];
  const float* W1 = (const float*)d_in[2];
  const float* b1 = (const float*)d_in[3];
  const float* W2 = (const float*)d_in[4];
  const float* b2 = (const float*)d_in[5];
  const float* W3 = (const float*)d_in[6];
  const float* b3 = (const float*)d_in[7];
  const float* Wc = (const float*)d_in[8];
  const float* bc = (const float*)d_in[9];
  float* out = (float*)d_out;

  const int n = NN;
  const int e = NE;
  const int* srcI = ei;       // row 0
  const int* dstI = ei + e;   // row 1

  // Workspace (32-bit words):
  //   dinv[N] | actA[N*24] | actB[N*12] | g[N*24] | cnt[N] | rowptr[N] |
  //   gtail[1024] | sbase[1024] | adj[E]
  // stg[NBA*CAPB = 7,194,400] ALIASES actA+actB (N*36 = 7,200,000 words):
  // stg is written by k_part / read by k_build, both BEFORE any act write.
  // Total = N*63 + 2048 + E words = 76.1 MB (R5 ran a 105 MB layout fully
  // in-bounds -- its error was bit-identical to R7's 67 MB layout).
  float* ws = (float*)d_ws;
  float* dinv = ws;
  float* actA = ws + n;                         // act1 (6 w) then act3 (24 w)
  float* actB = actA + (size_t)n * 24;          // act2 (12 w)
  float* g    = actB + (size_t)n * 12;          // fp32 messages, up to 24 w
  int* cnt    = (int*)(g + (size_t)n * 24);
  int* rowptr = cnt + n;
  int* gtail  = rowptr + n;
  int* sbase  = gtail + 1024;
  int* adj    = sbase + 1024;
  unsigned* stg = (unsigned*)actA;              // aliased staging (build-time only)

  const int gn = (n + BK - 1) / BK;

  // --- CSR build via binned counting sort (once; reused by 3 layers) ---
  k_zero<<<(NBA + BK - 1) / BK, BK, 0, stream>>>(gtail, NBA);
  k_part<<<GPART, BK, 0, stream>>>(srcI, dstI, stg, gtail, e);
  k_scan_sub<<<1, 512, 0, stream>>>(gtail, sbase);
  k_build<<<NBA, BK, 0, stream>>>(stg, gtail, sbase, cnt, rowptr, adj);
  k_dinv<<<gn, BK, 0, stream>>>(cnt, dinv, n);

  // --- Layer 1: x[N,3] -> act1 in actA[N,6], tanh ---
  k_transform<3, 6><<<gn, BK, 0, stream>>>(x, W1, dinv, g, n);
  k_gather<6, 0><<<gn, BK, 0, stream>>>(adj, rowptr, cnt, g, b1, dinv, actA, n);

  // --- Layer 2: actA[N,6] -> act2 in actB[N,12], l2norm+tanh ---
  k_transform<6, 12><<<gn, BK, 0, stream>>>(actA, W2, dinv, g, n);
  k_gather<12, 1><<<gn, BK, 0, stream>>>(adj, rowptr, cnt, g, b2, dinv, actB, n);

  // --- Layer 3: actB[N,12] -> act3 in actA[N,24], l2norm ---
  k_transform<12, 24><<<gn, BK, 0, stream>>>(actB, W3, dinv, g, n);
  k_gather<24, 2><<<gn, BK, 0, stream>>>(adj, rowptr, cnt, g, b3, dinv, actA, n);

  // --- Classifier: actA[N,24] -> out[N,13], l2norm ---
  k_classifier<<<gn, BK, 0, stream>>>(actA, Wc, bc, out, n);
}

// Round 9
// 722.430 us; speedup vs baseline: 19.3407x; 1.4616x over previous
//
#include <hip/hip_runtime.h>
#include <math.h>

// GCN on MI355X. N=200000 nodes, E=6400000 edges.
// R9: input-side aggregation. GCN linearity: sum norm*(x[s]@W) =
// dinv[d]*((sum dinv[s]*x[s]) @ W), so gather the PRE-transform features
// (width F_in: 16/32/64 B padded rows vs 24/48/96 B) and apply W after
// aggregation, fused into the gather epilogue (transforms + classifier
// kernels deleted). Source arrays shrink to 3.2/6.4/12.8 MB -> far better
// L2 residency (R8's F=24 gather fetched 804 MB = 2 lines/edge).
// Build: LDS-binned counting sort (R8-proven). MESSAGES STAY FP32 (bf16
// failed at 0.21 via l2norm amplification -- R7 bisect).

static constexpr int NN = 200000;
static constexpr int NE = 6400000;
static constexpr int BK = 256;

static constexpr int SUBW  = 512;                    // nodes per sub-bin (pow2)
static constexpr int NBA   = (NN + SUBW - 1) / SUBW; // 391 sub-bins
static constexpr int CAP   = 32;                     // LDS bin capacity (recs)
static constexpr int FLUSH = 16;                     // flush granule = 64B
static constexpr int CAPB  = 18400;                  // per-bin staging cap (+15.7 sigma), %16==0
static constexpr int GPART = 768;                    // k_part grid (50.4KB LDS -> 3 blocks/CU)

// ---------- pass 1: LDS-binned partition of edges into per-sub-bin staging ----------
__global__ void __launch_bounds__(BK) k_part(const int* __restrict__ srcI,
                                             const int* __restrict__ dstI,
                                             unsigned* __restrict__ stg,
                                             int* __restrict__ gtail, int e) {
  __shared__ unsigned bin[CAP][NBA];   // [slot][bin]: random-bin writes spread banks
  __shared__ int bcnt[NBA];
  for (int t = threadIdx.x; t < NBA; t += BK) bcnt[t] = 0;
  __syncthreads();
  int nchunks = (e + BK - 1) / BK;
  for (int c = blockIdx.x; c < nchunks; c += gridDim.x) {
    int i = c * BK + (int)threadIdx.x;
    if (i < e) {
      int d = __builtin_nontemporal_load(dstI + i);
      int s = __builtin_nontemporal_load(srcI + i);
      int b = d >> 9;                                        // sub-bin
      unsigned rec = ((unsigned)(d & (SUBW - 1)) << 18) | (unsigned)s;  // src < 2^18
      int p = atomicAdd(&bcnt[b], 1);
      if (p < CAP) {
        bin[p][b] = rec;
      } else {
        int base = atomicAdd(&gtail[b], 1);                  // rare overflow fallback
        stg[(size_t)b * CAPB + base] = rec;
      }
    }
    __syncthreads();
    // flush full 16-record (64B) chunks as 4x uint4 stores
    for (int b2 = threadIdx.x; b2 < NBA; b2 += BK) {
      int c2 = bcnt[b2];
      if (c2 > CAP) c2 = CAP;
      if (c2 >= FLUSH) {
        int nfl = c2 & ~(FLUSH - 1);
        int base = atomicAdd(&gtail[b2], nfl);
        size_t o = (size_t)b2 * CAPB + base;
        for (int k = 0; k < nfl; k += 4) {
          uint4 v;
          v.x = bin[k][b2]; v.y = bin[k + 1][b2]; v.z = bin[k + 2][b2]; v.w = bin[k + 3][b2];
          *(uint4*)(stg + o + k) = v;                        // base%16==0 -> aligned
        }
        int r = c2 - nfl;
        for (int k = 0; k < r; ++k) bin[k][b2] = bin[nfl + k][b2];
        bcnt[b2] = r;
      }
    }
    __syncthreads();
  }
  // final flush of residuals (scalar)
  for (int b2 = threadIdx.x; b2 < NBA; b2 += BK) {
    int c2 = bcnt[b2];
    if (c2 > CAP) c2 = CAP;
    if (c2 > 0) {
      int base = atomicAdd(&gtail[b2], c2);
      size_t o = (size_t)b2 * CAPB + base;
      for (int k = 0; k < c2; ++k) stg[o + k] = bin[k][b2];
    }
  }
}

// ---------- exclusive scan over sub-bin sizes (single block, 512 thr) ----------
__global__ void k_scan_sub(const int* __restrict__ gtail, int* __restrict__ sbase) {
  __shared__ int s0[512], s1[512];
  int t = threadIdx.x;
  int v = (t < NBA) ? gtail[t] : 0;
  s0[t] = v;
  __syncthreads();
  int* a = s0; int* b = s1;
  for (int off = 1; off < 512; off <<= 1) {
    int x = a[t] + ((t >= off) ? a[t - off] : 0);
    b[t] = x;
    __syncthreads();
    int* tmp = a; a = b; b = tmp;
  }
  if (t < NBA) sbase[t] = a[t] - v;  // exclusive
}

// ---------- pass 2: per-sub-bin hist + scan + scatter -> rowptr, adj ----------
__global__ void __launch_bounds__(BK) k_build(const unsigned* __restrict__ stg,
                                              const int* __restrict__ gtail,
                                              const int* __restrict__ sbase,
                                              int* __restrict__ rowptr,
                                              int* __restrict__ adj) {
  __shared__ int hist[SUBW];
  __shared__ int s0[SUBW], s1[SUBW];
  int b = blockIdx.x;
  int m = gtail[b]; if (m > CAPB) m = CAPB;
  size_t off = (size_t)b * CAPB;
  int base = sbase[b];
  if (b == NBA - 1 && threadIdx.x == 0) rowptr[NN] = base + m;  // dense total
  for (int t = threadIdx.x; t < SUBW; t += BK) hist[t] = 0;
  __syncthreads();
  for (int k = threadIdx.x; k < m; k += BK) atomicAdd(&hist[stg[off + k] >> 18], 1);
  __syncthreads();
  for (int t = threadIdx.x; t < SUBW; t += BK) s0[t] = hist[t];
  __syncthreads();
  int* a = s0; int* bb = s1;
  for (int o2 = 1; o2 < SUBW; o2 <<= 1) {
    for (int t = threadIdx.x; t < SUBW; t += BK) bb[t] = a[t] + ((t >= o2) ? a[t - o2] : 0);
    __syncthreads();
    int* tmp = a; a = bb; bb = tmp;
  }
  for (int t = threadIdx.x; t < SUBW; t += BK) {
    int node = b * SUBW + t;
    int ex = a[t] - hist[t];
    if (node < NN) rowptr[node] = base + ex;
    bb[t] = ex;  // cur init
  }
  __syncthreads();
  int* cur = bb;
  for (int k = threadIdx.x; k < m; k += BK) {
    unsigned rec = stg[off + k];
    int dl = rec >> 18;
    int p = atomicAdd(&cur[dl], 1);
    adj[base + p] = (int)(rec & 0x3FFFFu);  // single-block 64KB region: L2-resident
  }
}

__global__ void k_zero(int* __restrict__ p, int n) {
  int i = blockIdx.x * blockDim.x + threadIdx.x;
  if (i < n) p[i] = 0;
}

// counts = rowptr diff (dense packing from counting sort)
__global__ void k_dinv(const int* __restrict__ rowptr, float* __restrict__ dinv, int n) {
  int i = blockIdx.x * blockDim.x + threadIdx.x;
  if (i < n) dinv[i] = rsqrtf(1.0f + (float)(rowptr[i + 1] - rowptr[i]));
}

// p1[i] = dinv[i] * x[i]  (3 -> padded 4 words)
__global__ void k_prep(const float* __restrict__ x, const float* __restrict__ dinv,
                       float* __restrict__ p1, int n) {
  int i = blockIdx.x * blockDim.x + threadIdx.x;
  if (i >= n) return;
  float di = dinv[i];
  float4 v;
  v.x = di * x[3 * (size_t)i];
  v.y = di * x[3 * (size_t)i + 1];
  v.z = di * x[3 * (size_t)i + 2];
  v.w = 0.f;
  *(float4*)(p1 + 4 * (size_t)i) = v;
}

template <int PIN>
__device__ inline void row_add(const float* __restrict__ row, float* __restrict__ acc) {
#pragma unroll
  for (int j = 0; j < PIN; j += 4) {
    float4 v = *(const float4*)(row + j);  // PIN in {4,8,16}: 16B-aligned rows
    acc[j] += v.x; acc[j + 1] += v.y; acc[j + 2] += v.z; acc[j + 3] += v.w;
  }
}

// ---------- fused gather: q = sum p[s]; h = dinv*(q@W)+b; act; p_out = dinv*act ----------
// MODE 0: tanh   MODE 1: l2norm then tanh
template <int PIN, int FIN, int FOUT, int POUT, int MODE>
__global__ void __launch_bounds__(BK) k_gather_fused(
    const int* __restrict__ adj, const int* __restrict__ rowptr,
    const float* __restrict__ pin, const float* __restrict__ W,
    const float* __restrict__ bias, const float* __restrict__ dinv,
    float* __restrict__ pout, int n) {
  __shared__ float sW[FIN * FOUT];
  __shared__ float sb[FOUT];
  for (int t = threadIdx.x; t < FIN * FOUT; t += BK) sW[t] = W[t];
  if (threadIdx.x < FOUT) sb[threadIdx.x] = bias[threadIdx.x];
  __syncthreads();
  int i = blockIdx.x * blockDim.x + threadIdx.x;
  if (i >= n) return;
  float acc[PIN] = {};
  row_add<PIN>(pin + (size_t)i * PIN, acc);  // self-loop
  int st = rowptr[i], en = rowptr[i + 1];
  int k = st;
  for (; k + 4 <= en; k += 4) {              // 4-way MLP
    int s0 = adj[k], s1 = adj[k + 1], s2 = adj[k + 2], s3 = adj[k + 3];
    row_add<PIN>(pin + (size_t)s0 * PIN, acc);
    row_add<PIN>(pin + (size_t)s1 * PIN, acc);
    row_add<PIN>(pin + (size_t)s2 * PIN, acc);
    row_add<PIN>(pin + (size_t)s3 * PIN, acc);
  }
  for (; k < en; ++k) row_add<PIN>(pin + (size_t)adj[k] * PIN, acc);
  float di = dinv[i];
  float h[FOUT];
  float ss = 0.f;
#pragma unroll
  for (int j = 0; j < FOUT; ++j) {
    float s = 0.f;
#pragma unroll
    for (int kk = 0; kk < FIN; ++kk) s = fmaf(acc[kk], sW[kk * FOUT + j], s);
    float t = fmaf(di, s, sb[j]);
    h[j] = t;
    ss += t * t;
  }
  float o[POUT];
#pragma unroll
  for (int j = 0; j < POUT; ++j) o[j] = 0.f;
  if (MODE == 0) {
#pragma unroll
    for (int j = 0; j < FOUT; ++j) o[j] = di * tanhf(h[j]);
  } else {
    float inv = 1.f / fmaxf(sqrtf(ss), 1e-12f);
#pragma unroll
    for (int j = 0; j < FOUT; ++j) o[j] = di * tanhf(h[j] * inv);
  }
  float* po = pout + (size_t)i * POUT;
#pragma unroll
  for (int j = 0; j < POUT; j += 4) *(float4*)(po + j) = make_float4(o[j], o[j+1], o[j+2], o[j+3]);
}

// ---------- final: gather(F_in=12) -> W3 -> l2norm -> Wc -> l2norm -> out ----------
__global__ void __launch_bounds__(BK) k_gather_final(
    const int* __restrict__ adj, const int* __restrict__ rowptr,
    const float* __restrict__ pin, const float* __restrict__ W3,
    const float* __restrict__ b3, const float* __restrict__ Wc,
    const float* __restrict__ bc, const float* __restrict__ dinv,
    float* __restrict__ out, int n) {
  constexpr int PIN = 16, FIN = 12, FOUT = 24, FC = 13;
  __shared__ float sW[FIN * FOUT];
  __shared__ float sb[FOUT];
  __shared__ float sWc[FOUT * FC];
  __shared__ float sbc[FC];
  for (int t = threadIdx.x; t < FIN * FOUT; t += BK) sW[t] = W3[t];
  for (int t = threadIdx.x; t < FOUT * FC; t += BK) sWc[t] = Wc[t];
  if (threadIdx.x < FOUT) sb[threadIdx.x] = b3[threadIdx.x];
  if (threadIdx.x < FC) sbc[threadIdx.x] = bc[threadIdx.x];
  __syncthreads();
  int i = blockIdx.x * blockDim.x + threadIdx.x;
  if (i >= n) return;
  float acc[PIN] = {};
  row_add<PIN>(pin + (size_t)i * PIN, acc);
  int st = rowptr[i], en = rowptr[i + 1];
  int k = st;
  for (; k + 4 <= en; k += 4) {
    int s0 = adj[k], s1 = adj[k + 1], s2 = adj[k + 2], s3 = adj[k + 3];
    row_add<PIN>(pin + (size_t)s0 * PIN, acc);
    row_add<PIN>(pin + (size_t)s1 * PIN, acc);
    row_add<PIN>(pin + (size_t)s2 * PIN, acc);
    row_add<PIN>(pin + (size_t)s3 * PIN, acc);
  }
  for (; k < en; ++k) row_add<PIN>(pin + (size_t)adj[k] * PIN, acc);
  float di = dinv[i];
  float h[FOUT];
  float ss = 0.f;
#pragma unroll
  for (int j = 0; j < FOUT; ++j) {
    float s = 0.f;
#pragma unroll
    for (int kk = 0; kk < FIN; ++kk) s = fmaf(acc[kk], sW[kk * FOUT + j], s);
    float t = fmaf(di, s, sb[j]);
    h[j] = t;
    ss += t * t;
  }
  float inv = 1.f / fmaxf(sqrtf(ss), 1e-12f);   // act3 = l2norm(h)
  float v[FC];
  float ss2 = 0.f;
#pragma unroll
  for (int j = 0; j < FC; ++j) {
    float s = sbc[j];
#pragma unroll
    for (int kk = 0; kk < FOUT; ++kk) s = fmaf(h[kk] * inv, sWc[kk * FC + j], s);
    v[j] = s;
    ss2 += s * s;
  }
  float inv2 = 1.f / fmaxf(sqrtf(ss2), 1e-12f);
#pragma unroll
  for (int j = 0; j < FC; ++j) out[(size_t)i * FC + j] = v[j] * inv2;
}

extern "C" void kernel_launch(void* const* d_in, const int* in_sizes, int n_in,
                              void* d_out, int out_size, void* d_ws, size_t ws_size,
                              hipStream_t stream) {
  const float* x  = (const float*)d_in[0];
  const int*   ei = (const int*)d_in[1];
  const float* W1 = (const float*)d_in[2];
  const float* b1 = (const float*)d_in[3];
  const float* W2 = (const float*)d_in[4];
  const float* b2 = (const float*)d_in[5];
  const float* W3 = (const float*)d_in[6];
  const float* b3 = (const float*)d_in[7];
  const float* Wc = (const float*)d_in[8];
  const float* bc = (const float*)d_in[9];
  float* out = (float*)d_out;

  const int n = NN;
  const int e = NE;
  const int* srcI = ei;       // row 0
  const int* dstI = ei + e;   // row 1

  // Workspace (words):
  //   dinv[N] | rowptr[N+8] | gtail[512] | sbase[512] | adj[E] | R[NBA*CAPB]
  // R hosts stg during build, then p1[4N] | p2[8N] | p3[16N] (28N <= 36N):
  // stg dead after k_build; p's written strictly afterwards.
  // Total = 6,801,032 + 7,194,400 words = 56.0 MB (< 76.1 MB proven in R8).
  float* ws = (float*)d_ws;
  float* dinv  = ws;
  int* rowptr  = (int*)(ws + n);            // N+8 (uses N+1, padded for alignment)
  int* gtail   = rowptr + n + 8;
  int* sbase   = gtail + 512;
  int* adj     = sbase + 512;
  float* R     = (float*)(adj + (size_t)e); // 16B-aligned (offset 6,801,032 words)
  unsigned* stg = (unsigned*)R;
  float* p1 = R;                            // 4N
  float* p2 = R + (size_t)4 * n;            // 8N
  float* p3 = R + (size_t)12 * n;           // 16N

  const int gn = (n + BK - 1) / BK;

  // --- CSR build via binned counting sort (reused by all 3 layers) ---
  k_zero<<<2, BK, 0, stream>>>(gtail, 512);
  k_part<<<GPART, BK, 0, stream>>>(srcI, dstI, stg, gtail, e);
  k_scan_sub<<<1, 512, 0, stream>>>(gtail, sbase);
  k_build<<<NBA, BK, 0, stream>>>(stg, gtail, sbase, rowptr, adj);
  k_dinv<<<gn, BK, 0, stream>>>(rowptr, dinv, n);

  // --- p1 = dinv * x ---
  k_prep<<<gn, BK, 0, stream>>>(x, dinv, p1, n);

  // --- Layer 1: gather p1 (16B rows) -> W1 -> tanh -> p2 = dinv*act ---
  k_gather_fused<4, 3, 6, 8, 0><<<gn, BK, 0, stream>>>(adj, rowptr, p1, W1, b1, dinv, p2, n);

  // --- Layer 2: gather p2 (32B rows) -> W2 -> l2norm+tanh -> p3 = dinv*act ---
  k_gather_fused<8, 6, 12, 16, 1><<<gn, BK, 0, stream>>>(adj, rowptr, p2, W2, b2, dinv, p3, n);

  // --- Layer 3 + classifier: gather p3 (64B rows) -> W3 -> l2norm -> Wc -> l2norm -> out ---
  k_gather_final<<<gn, BK, 0, stream>>>(adj, rowptr, p3, W3, b3, Wc, bc, dinv, out, n);
}

// Round 10
// 611.210 us; speedup vs baseline: 22.8600x; 1.1820x over previous
//
#include <hip/hip_runtime.h>
#include <math.h>

// GCN on MI355X. N=200000 nodes, E=6400000 edges.
// R10: k_part was 198 us with nothing saturated (HBM 4%, VALU 5%, occ 30%) --
// latency/serialization bound: 25000 chunks x (2 barriers + 391-bin flush sweep
// + dependent LDS->global-atomic->LDS flush chain) for only 256 edges each.
// Now: 512-thread blocks x 4 edges/thread = 2048 edges/chunk (8x fewer
// barriers/sweeps), batched edge loads, single-pass flush sweep, 24 waves/CU.
// Pipeline (R9-proven): LDS-binned counting-sort CSR build + input-side
// aggregation gathers (GCN linearity). MESSAGES STAY FP32 (bf16 fails 0.21
// via l2norm amplification -- R7 bisect).

static constexpr int NN = 200000;
static constexpr int NE = 6400000;
static constexpr int BK = 256;

static constexpr int SUBW  = 512;                    // nodes per sub-bin (pow2)
static constexpr int NBA   = (NN + SUBW - 1) / SUBW; // 391 sub-bins
static constexpr int CAP   = 32;                     // LDS bin capacity (recs)
static constexpr int FLUSH = 16;                     // flush granule = 64B
static constexpr int CAPB  = 18400;                  // per-bin staging cap (+15.7 sigma), %16==0
static constexpr int BKP   = 512;                    // k_part block threads
static constexpr int EPT   = 4;                      // edges per thread per chunk
static constexpr int CHUNK = BKP * EPT;              // 2048 edges per chunk
static constexpr int GPART = 768;                    // 3 blocks/CU (LDS-limited)

// ---------- pass 1: LDS-binned partition of edges into per-sub-bin staging ----------
__global__ void __launch_bounds__(BKP) k_part(const int* __restrict__ srcI,
                                              const int* __restrict__ dstI,
                                              unsigned* __restrict__ stg,
                                              int* __restrict__ gtail, int e) {
  __shared__ unsigned bin[CAP][NBA];   // [slot][bin]: random-bin writes spread banks
  __shared__ int bcnt[NBA];
  for (int t = threadIdx.x; t < NBA; t += BKP) bcnt[t] = 0;
  __syncthreads();
  int nchunks = (e + CHUNK - 1) / CHUNK;
  for (int c = blockIdx.x; c < nchunks; c += gridDim.x) {
    int base_i = c * CHUNK;
    int dv[EPT], sv[EPT];
    // batched loads: all 2*EPT loads in flight before any use
#pragma unroll
    for (int u = 0; u < EPT; ++u) {
      int i = base_i + u * BKP + (int)threadIdx.x;
      dv[u] = (i < e) ? __builtin_nontemporal_load(dstI + i) : -1;
      sv[u] = (i < e) ? __builtin_nontemporal_load(srcI + i) : 0;
    }
#pragma unroll
    for (int u = 0; u < EPT; ++u) {
      if (dv[u] >= 0) {
        int b = dv[u] >> 9;
        unsigned rec = ((unsigned)(dv[u] & (SUBW - 1)) << 18) | (unsigned)sv[u];
        int p = atomicAdd(&bcnt[b], 1);
        if (p < CAP) {
          bin[p][b] = rec;
        } else {
          int base = atomicAdd(&gtail[b], 1);               // rare overflow fallback
          stg[(size_t)b * CAPB + base] = rec;
        }
      }
    }
    __syncthreads();
    // single-pass flush sweep (BKP=512 >= NBA=391)
    int b2 = threadIdx.x;
    if (b2 < NBA) {
      int c2 = bcnt[b2];
      if (c2 > CAP) c2 = CAP;
      if (c2 >= FLUSH) {
        int nfl = c2 & ~(FLUSH - 1);
        int base = atomicAdd(&gtail[b2], nfl);
        size_t o = (size_t)b2 * CAPB + base;
        for (int k = 0; k < nfl; k += 4) {
          uint4 v;
          v.x = bin[k][b2]; v.y = bin[k + 1][b2]; v.z = bin[k + 2][b2]; v.w = bin[k + 3][b2];
          *(uint4*)(stg + o + k) = v;                       // base%16==0 -> aligned
        }
        int r = c2 - nfl;
        for (int k = 0; k < r; ++k) bin[k][b2] = bin[nfl + k][b2];
        bcnt[b2] = r;
      }
    }
    __syncthreads();
  }
  // final flush of residuals (scalar)
  int b2 = threadIdx.x;
  if (b2 < NBA) {
    int c2 = bcnt[b2];
    if (c2 > CAP) c2 = CAP;
    if (c2 > 0) {
      int base = atomicAdd(&gtail[b2], c2);
      size_t o = (size_t)b2 * CAPB + base;
      for (int k = 0; k < c2; ++k) stg[o + k] = bin[k][b2];
    }
  }
}

// ---------- exclusive scan over sub-bin sizes (single block, 512 thr) ----------
__global__ void k_scan_sub(const int* __restrict__ gtail, int* __restrict__ sbase) {
  __shared__ int s0[512], s1[512];
  int t = threadIdx.x;
  int v = (t < NBA) ? gtail[t] : 0;
  s0[t] = v;
  __syncthreads();
  int* a = s0; int* b = s1;
  for (int off = 1; off < 512; off <<= 1) {
    int x = a[t] + ((t >= off) ? a[t - off] : 0);
    b[t] = x;
    __syncthreads();
    int* tmp = a; a = b; b = tmp;
  }
  if (t < NBA) sbase[t] = a[t] - v;  // exclusive
}

// ---------- pass 2: per-sub-bin hist + scan + scatter -> rowptr, adj ----------
__global__ void __launch_bounds__(BK) k_build(const unsigned* __restrict__ stg,
                                              const int* __restrict__ gtail,
                                              const int* __restrict__ sbase,
                                              int* __restrict__ rowptr,
                                              int* __restrict__ adj) {
  __shared__ int hist[SUBW];
  __shared__ int s0[SUBW], s1[SUBW];
  int b = blockIdx.x;
  int m = gtail[b]; if (m > CAPB) m = CAPB;
  size_t off = (size_t)b * CAPB;
  int base = sbase[b];
  if (b == NBA - 1 && threadIdx.x == 0) rowptr[NN] = base + m;  // dense total
  for (int t = threadIdx.x; t < SUBW; t += BK) hist[t] = 0;
  __syncthreads();
  for (int k = threadIdx.x; k < m; k += BK) atomicAdd(&hist[stg[off + k] >> 18], 1);
  __syncthreads();
  for (int t = threadIdx.x; t < SUBW; t += BK) s0[t] = hist[t];
  __syncthreads();
  int* a = s0; int* bb = s1;
  for (int o2 = 1; o2 < SUBW; o2 <<= 1) {
    for (int t = threadIdx.x; t < SUBW; t += BK) bb[t] = a[t] + ((t >= o2) ? a[t - o2] : 0);
    __syncthreads();
    int* tmp = a; a = bb; bb = tmp;
  }
  for (int t = threadIdx.x; t < SUBW; t += BK) {
    int node = b * SUBW + t;
    int ex = a[t] - hist[t];
    if (node < NN) rowptr[node] = base + ex;
    bb[t] = ex;  // cur init
  }
  __syncthreads();
  int* cur = bb;
  for (int k = threadIdx.x; k < m; k += BK) {
    unsigned rec = stg[off + k];
    int dl = rec >> 18;
    int p = atomicAdd(&cur[dl], 1);
    adj[base + p] = (int)(rec & 0x3FFFFu);  // single-block 64KB region: L2-resident
  }
}

__global__ void k_zero(int* __restrict__ p, int n) {
  int i = blockIdx.x * blockDim.x + threadIdx.x;
  if (i < n) p[i] = 0;
}

// counts = rowptr diff (dense packing from counting sort)
__global__ void k_dinv(const int* __restrict__ rowptr, float* __restrict__ dinv, int n) {
  int i = blockIdx.x * blockDim.x + threadIdx.x;
  if (i < n) dinv[i] = rsqrtf(1.0f + (float)(rowptr[i + 1] - rowptr[i]));
}

// p1[i] = dinv[i] * x[i]  (3 -> padded 4 words)
__global__ void k_prep(const float* __restrict__ x, const float* __restrict__ dinv,
                       float* __restrict__ p1, int n) {
  int i = blockIdx.x * blockDim.x + threadIdx.x;
  if (i >= n) return;
  float di = dinv[i];
  float4 v;
  v.x = di * x[3 * (size_t)i];
  v.y = di * x[3 * (size_t)i + 1];
  v.z = di * x[3 * (size_t)i + 2];
  v.w = 0.f;
  *(float4*)(p1 + 4 * (size_t)i) = v;
}

template <int PIN>
__device__ inline void row_add(const float* __restrict__ row, float* __restrict__ acc) {
#pragma unroll
  for (int j = 0; j < PIN; j += 4) {
    float4 v = *(const float4*)(row + j);  // PIN in {4,8,16}: 16B-aligned rows
    acc[j] += v.x; acc[j + 1] += v.y; acc[j + 2] += v.z; acc[j + 3] += v.w;
  }
}

// ---------- fused gather: q = sum p[s]; h = dinv*(q@W)+b; act; p_out = dinv*act ----------
// MODE 0: tanh   MODE 1: l2norm then tanh
template <int PIN, int FIN, int FOUT, int POUT, int MODE>
__global__ void __launch_bounds__(BK) k_gather_fused(
    const int* __restrict__ adj, const int* __restrict__ rowptr,
    const float* __restrict__ pin, const float* __restrict__ W,
    const float* __restrict__ bias, const float* __restrict__ dinv,
    float* __restrict__ pout, int n) {
  __shared__ float sW[FIN * FOUT];
  __shared__ float sb[FOUT];
  for (int t = threadIdx.x; t < FIN * FOUT; t += BK) sW[t] = W[t];
  if (threadIdx.x < FOUT) sb[threadIdx.x] = bias[threadIdx.x];
  __syncthreads();
  int i = blockIdx.x * blockDim.x + threadIdx.x;
  if (i >= n) return;
  float acc[PIN] = {};
  row_add<PIN>(pin + (size_t)i * PIN, acc);  // self-loop
  int st = rowptr[i], en = rowptr[i + 1];
  int k = st;
  for (; k + 4 <= en; k += 4) {              // 4-way MLP
    int s0 = adj[k], s1 = adj[k + 1], s2 = adj[k + 2], s3 = adj[k + 3];
    row_add<PIN>(pin + (size_t)s0 * PIN, acc);
    row_add<PIN>(pin + (size_t)s1 * PIN, acc);
    row_add<PIN>(pin + (size_t)s2 * PIN, acc);
    row_add<PIN>(pin + (size_t)s3 * PIN, acc);
  }
  for (; k < en; ++k) row_add<PIN>(pin + (size_t)adj[k] * PIN, acc);
  float di = dinv[i];
  float h[FOUT];
  float ss = 0.f;
#pragma unroll
  for (int j = 0; j < FOUT; ++j) {
    float s = 0.f;
#pragma unroll
    for (int kk = 0; kk < FIN; ++kk) s = fmaf(acc[kk], sW[kk * FOUT + j], s);
    float t = fmaf(di, s, sb[j]);
    h[j] = t;
    ss += t * t;
  }
  float o[POUT];
#pragma unroll
  for (int j = 0; j < POUT; ++j) o[j] = 0.f;
  if (MODE == 0) {
#pragma unroll
    for (int j = 0; j < FOUT; ++j) o[j] = di * tanhf(h[j]);
  } else {
    float inv = 1.f / fmaxf(sqrtf(ss), 1e-12f);
#pragma unroll
    for (int j = 0; j < FOUT; ++j) o[j] = di * tanhf(h[j] * inv);
  }
  float* po = pout + (size_t)i * POUT;
#pragma unroll
  for (int j = 0; j < POUT; j += 4) *(float4*)(po + j) = make_float4(o[j], o[j+1], o[j+2], o[j+3]);
}

// ---------- final: gather(F_in=12) -> W3 -> l2norm -> Wc -> l2norm -> out ----------
__global__ void __launch_bounds__(BK) k_gather_final(
    const int* __restrict__ adj, const int* __restrict__ rowptr,
    const float* __restrict__ pin, const float* __restrict__ W3,
    const float* __restrict__ b3, const float* __restrict__ Wc,
    const float* __restrict__ bc, const float* __restrict__ dinv,
    float* __restrict__ out, int n) {
  constexpr int PIN = 16, FIN = 12, FOUT = 24, FC = 13;
  __shared__ float sW[FIN * FOUT];
  __shared__ float sb[FOUT];
  __shared__ float sWc[FOUT * FC];
  __shared__ float sbc[FC];
  for (int t = threadIdx.x; t < FIN * FOUT; t += BK) sW[t] = W3[t];
  for (int t = threadIdx.x; t < FOUT * FC; t += BK) sWc[t] = Wc[t];
  if (threadIdx.x < FOUT) sb[threadIdx.x] = b3[threadIdx.x];
  if (threadIdx.x < FC) sbc[threadIdx.x] = bc[threadIdx.x];
  __syncthreads();
  int i = blockIdx.x * blockDim.x + threadIdx.x;
  if (i >= n) return;
  float acc[PIN] = {};
  row_add<PIN>(pin + (size_t)i * PIN, acc);
  int st = rowptr[i], en = rowptr[i + 1];
  int k = st;
  for (; k + 4 <= en; k += 4) {
    int s0 = adj[k], s1 = adj[k + 1], s2 = adj[k + 2], s3 = adj[k + 3];
    row_add<PIN>(pin + (size_t)s0 * PIN, acc);
    row_add<PIN>(pin + (size_t)s1 * PIN, acc);
    row_add<PIN>(pin + (size_t)s2 * PIN, acc);
    row_add<PIN>(pin + (size_t)s3 * PIN, acc);
  }
  for (; k < en; ++k) row_add<PIN>(pin + (size_t)adj[k] * PIN, acc);
  float di = dinv[i];
  float h[FOUT];
  float ss = 0.f;
#pragma unroll
  for (int j = 0; j < FOUT; ++j) {
    float s = 0.f;
#pragma unroll
    for (int kk = 0; kk < FIN; ++kk) s = fmaf(acc[kk], sW[kk * FOUT + j], s);
    float t = fmaf(di, s, sb[j]);
    h[j] = t;
    ss += t * t;
  }
  float inv = 1.f / fmaxf(sqrtf(ss), 1e-12f);   // act3 = l2norm(h)
  float v[FC];
  float ss2 = 0.f;
#pragma unroll
  for (int j = 0; j < FC; ++j) {
    float s = sbc[j];
#pragma unroll
    for (int kk = 0; kk < FOUT; ++kk) s = fmaf(h[kk] * inv, sWc[kk * FC + j], s);
    v[j] = s;
    ss2 += s * s;
  }
  float inv2 = 1.f / fmaxf(sqrtf(ss2), 1e-12f);
#pragma unroll
  for (int j = 0; j < FC; ++j) out[(size_t)i * FC + j] = v[j] * inv2;
}

extern "C" void kernel_launch(void* const* d_in, const int* in_sizes, int n_in,
                              void* d_out, int out_size, void* d_ws, size_t ws_size,
                              hipStream_t stream) {
  const float* x  = (const float*)d_in[0];
  const int*   ei = (const int*)d_in[1];
  const float* W1 = (const float*)d_in[2];
  const float* b1 = (const float*)d_in[3];
  const float* W2 = (const float*)d_in[4];
  const float* b2 = (const float*)d_in[5];
  const float* W3 = (const float*)d_in[6];
  const float* b3 = (const float*)d_in[7];
  const float* Wc = (const float*)d_in[8];
  const float* bc = (const float*)d_in[9];
  float* out = (float*)d_out;

  const int n = NN;
  const int e = NE;
  const int* srcI = ei;       // row 0
  const int* dstI = ei + e;   // row 1

  // Workspace (words):
  //   dinv[N] | rowptr[N+8] | gtail[512] | sbase[512] | adj[E] | R[NBA*CAPB]
  // R hosts stg during build, then p1[4N] | p2[8N] | p3[16N] (28N <= 36N):
  // stg dead after k_build; p's written strictly afterwards.
  // Total = 6,801,032 + 7,194,400 words = 56.0 MB (R8 proved >= 76 MB safe).
  float* ws = (float*)d_ws;
  float* dinv  = ws;
  int* rowptr  = (int*)(ws + n);            // N+8 (uses N+1, padded for alignment)
  int* gtail   = rowptr + n + 8;
  int* sbase   = gtail + 512;
  int* adj     = sbase + 512;
  float* R     = (float*)(adj + (size_t)e); // 16B-aligned
  unsigned* stg = (unsigned*)R;
  float* p1 = R;                            // 4N
  float* p2 = R + (size_t)4 * n;            // 8N
  float* p3 = R + (size_t)12 * n;           // 16N

  const int gn = (n + BK - 1) / BK;

  // --- CSR build via binned counting sort (reused by all 3 layers) ---
  k_zero<<<2, BK, 0, stream>>>(gtail, 512);
  k_part<<<GPART, BKP, 0, stream>>>(srcI, dstI, stg, gtail, e);
  k_scan_sub<<<1, 512, 0, stream>>>(gtail, sbase);
  k_build<<<NBA, BK, 0, stream>>>(stg, gtail, sbase, rowptr, adj);
  k_dinv<<<gn, BK, 0, stream>>>(rowptr, dinv, n);

  // --- p1 = dinv * x ---
  k_prep<<<gn, BK, 0, stream>>>(x, dinv, p1, n);

  // --- Layer 1: gather p1 (16B rows) -> W1 -> tanh -> p2 = dinv*act ---
  k_gather_fused<4, 3, 6, 8, 0><<<gn, BK, 0, stream>>>(adj, rowptr, p1, W1, b1, dinv, p2, n);

  // --- Layer 2: gather p2 (32B rows) -> W2 -> l2norm+tanh -> p3 = dinv*act ---
  k_gather_fused<8, 6, 12, 16, 1><<<gn, BK, 0, stream>>>(adj, rowptr, p2, W2, b2, dinv, p3, n);

  // --- Layer 3 + classifier: gather p3 (64B rows) -> W3 -> l2norm -> Wc -> l2norm -> out ---
  k_gather_final<<<gn, BK, 0, stream>>>(adj, rowptr, p3, W3, b3, Wc, bc, dinv, out, n);
}